// Round 2
// baseline (2421.534 us; speedup 1.0000x reference)
//
#include <hip/hip_runtime.h>

#define NSV 20
#define SS  1000

typedef __bf16 bf16_t;
typedef __bf16 bf16x8 __attribute__((ext_vector_type(8)));
typedef float  f32x4  __attribute__((ext_vector_type(4)));

__device__ __forceinline__ float selu_f(float v) {
    const float scale = 1.0507009873554805f;
    const float alpha = 1.6732632423543772f;
    return v > 0.f ? scale * v : scale * alpha * expm1f(v);
}

// ---------------------------------------------------------------------------
// RNN kernel: one block per batch row, 512 threads (8 waves/CU).
// Threads (4j..4j+3) compute hidden unit j; each holds a 32-wide slice of the
// weight row in registers (~103 fp32/thread -> no spill at 256-VGPR cap).
// Combine quarters with __shfl_xor(1) + __shfl_xor(2).
// Quarter-rotated LDS reads ((i+2q)&7) -> disjoint bank groups, conflict-free.
// 4 barriers/step: h0/dt prefetch for t+1 is folded into the L3 phase.
// ---------------------------------------------------------------------------
__global__ __launch_bounds__(512, 2) void rnn_kernel(
    const float* __restrict__ x,
    const float* __restrict__ gw0, const float* __restrict__ gb0,
    const float* __restrict__ gw1, const float* __restrict__ gb1,
    const float* __restrict__ gw2, const float* __restrict__ gb2,
    const float* __restrict__ gw3, const float* __restrict__ gb3,
    float* __restrict__ statevar)
{
    const int b   = blockIdx.x;
    const int tid = threadIdx.x;
    const int j   = tid >> 2;   // hidden unit 0..127
    const int q   = tid & 3;    // quarter 0..3

    __shared__ __align__(16) float h0buf[28];   // [eps(6), sv(20), pad0(2)]
    __shared__ __align__(16) float hA[128];
    __shared__ __align__(16) float hB[128];
    __shared__ __align__(16) float hC[128];
    __shared__ float sdt[2];

    // ---- weights into registers (no spill: ~103 fp32/thread) ----
    float w0[7];
#pragma unroll
    for (int i = 0; i < 7; ++i) {
        int c = q * 7 + i;                      // 0..27
        w0[i] = (c < 26) ? gw0[j * 26 + c] : 0.f;
    }
    float w1[32], w2[32], w3[32];
#pragma unroll
    for (int i = 0; i < 32; ++i) w1[i] = gw1[j * 128 + q * 32 + i];
#pragma unroll
    for (int i = 0; i < 32; ++i) w2[i] = gw2[j * 128 + q * 32 + i];
    if (j < NSV) {
#pragma unroll
        for (int i = 0; i < 32; ++i) w3[i] = gw3[j * 128 + q * 32 + i];
    }
    const float b0 = gb0[j];
    const float b1 = gb1[j];
    const float b2 = gb2[j];
    const float b3 = (j < NSV) ? gb3[j] : 0.f;

    const float* xb = x + b * (SS * 13);

    // ---- init: h0 = [eps(0), sv0=0, pad=0], dt(0), statevar[:,0,:]=0 ----
    if (tid < 6)                 h0buf[tid] = xb[1 + tid];
    else if (tid < 28)           h0buf[tid] = 0.f;
    if (tid == 28)               sdt[0] = xb[13] - xb[0];
    if (tid < NSV)               statevar[b * (SS * NSV) + tid] = 0.f;
    __syncthreads();

    // 32-wide dot with quarter-rotated phase: conflict-free LDS broadcast
#define DOT32(W, BASE, OUT) do {                                    \
        const float4* h4_ = (const float4*)(BASE);                  \
        float s0_ = 0.f, s1_ = 0.f, s2_ = 0.f, s3_ = 0.f;           \
        _Pragma("unroll")                                           \
        for (int i_ = 0; i_ < 8; ++i_) {                            \
            const int ii_ = (i_ + 2 * q) & 7;                       \
            float4 hv_ = h4_[ii_];                                  \
            s0_ = fmaf(W[4*ii_+0], hv_.x, s0_);                     \
            s1_ = fmaf(W[4*ii_+1], hv_.y, s1_);                     \
            s2_ = fmaf(W[4*ii_+2], hv_.z, s2_);                     \
            s3_ = fmaf(W[4*ii_+3], hv_.w, s3_);                     \
        }                                                           \
        OUT = (s0_ + s1_) + (s2_ + s3_);                            \
    } while (0)

    for (int t = 0; t < SS - 1; ++t) {
        // L0: 28 -> 128 (h0buf[26..27] are permanent zeros)
        {
            float s0 = 0.f, s1 = 0.f;
            const float* hh = &h0buf[q * 7];
#pragma unroll
            for (int i = 0; i < 6; i += 2) {
                s0 = fmaf(w0[i + 0], hh[i + 0], s0);
                s1 = fmaf(w0[i + 1], hh[i + 1], s1);
            }
            s0 = fmaf(w0[6], hh[6], s0);
            float s = s0 + s1;
            s += __shfl_xor(s, 1, 64);
            s += __shfl_xor(s, 2, 64);
            if (q == 0) hA[j] = selu_f(s + b0);
        }
        __syncthreads();

        // L1: 128 -> 128  (hA -> hB)
        {
            float s;
            DOT32(w1, &hA[q * 32], s);
            s += __shfl_xor(s, 1, 64);
            s += __shfl_xor(s, 2, 64);
            if (q == 0) hB[j] = selu_f(s + b1);
        }
        __syncthreads();

        // L2: 128 -> 128  (hB -> hC)
        {
            float s;
            DOT32(w2, &hB[q * 32], s);
            s += __shfl_xor(s, 1, 64);
            s += __shfl_xor(s, 2, 64);
            if (q == 0) hC[j] = selu_f(s + b2);
        }
        __syncthreads();

        // L3: 128 -> 20, integrate sv into h0buf; prefetch eps/dt for t+1
        if (j < NSV) {
            float s;
            DOT32(w3, &hC[q * 32], s);
            s += __shfl_xor(s, 1, 64);
            s += __shfl_xor(s, 2, 64);
            if (q == 0) {
                float svd = s + b3;
                float ns  = h0buf[6 + j] + sdt[t & 1] * svd;
                h0buf[6 + j] = ns;
                statevar[b * (SS * NSV) + (t + 1) * NSV + j] = ns;
            }
        }
        if (tid >= 128 && tid < 134)
            h0buf[tid - 128] = xb[(t + 1) * 13 + 1 + (tid - 128)];
        if (tid == 140 && t + 2 < SS)
            sdt[(t + 1) & 1] = xb[(t + 2) * 13] - xb[(t + 1) * 13];
        __syncthreads();
    }
#undef DOT32
}

// ---------------------------------------------------------------------------
// Weight prep: fp32 -> bf16, pad fw3 from [6][256] to [16][256] with zeros.
// ---------------------------------------------------------------------------
__global__ void prep_weights(
    const float* __restrict__ fw0, const float* __restrict__ fw1,
    const float* __restrict__ fw2, const float* __restrict__ fw3,
    bf16_t* __restrict__ w0b, bf16_t* __restrict__ w1b,
    bf16_t* __restrict__ w2b, bf16_t* __restrict__ w3b)
{
    const int i      = blockIdx.x * blockDim.x + threadIdx.x;
    const int stride = gridDim.x * blockDim.x;
    for (int k = i; k < 256 * 32;  k += stride) w0b[k] = (bf16_t)fw0[k];
    for (int k = i; k < 256 * 256; k += stride) w1b[k] = (bf16_t)fw1[k];
    for (int k = i; k < 256 * 256; k += stride) w2b[k] = (bf16_t)fw2[k];
    for (int k = i; k < 16 * 256;  k += stride) {
        int row = k >> 8, col = k & 255;
        w3b[k] = (row < 6) ? (bf16_t)fw3[row * 256 + col] : (bf16_t)0.f;
    }
}

// ---------------------------------------------------------------------------
// Fused F-MLP: 64-row tiles, bf16 MFMA 16x16x32, fp32 accumulate.
// 4 waves; each wave computes all 64 rows x its 64 output columns.
// ---------------------------------------------------------------------------
#define LDA 264   // 256 + 8 pad

template <int K>
__device__ __forceinline__ void mlp_layer(
    bf16_t* __restrict__ A, const bf16_t* __restrict__ Wb,
    const float* __restrict__ bias, int wave, int lane, bool do_selu)
{
    f32x4 acc[4][4];
#pragma unroll
    for (int mt = 0; mt < 4; ++mt)
#pragma unroll
        for (int nt = 0; nt < 4; ++nt) acc[mt][nt] = (f32x4){0.f, 0.f, 0.f, 0.f};

    const int colbase = wave * 64;
    const int mrow = lane & 15;
    const int quad = lane >> 4;

#pragma unroll
    for (int ks = 0; ks < K / 32; ++ks) {
        bf16x8 af[4], bfr[4];
#pragma unroll
        for (int mt = 0; mt < 4; ++mt)
            af[mt] = *(const bf16x8*)&A[(mt * 16 + mrow) * LDA + ks * 32 + quad * 8];
#pragma unroll
        for (int nt = 0; nt < 4; ++nt)
            bfr[nt] = *(const bf16x8*)&Wb[(colbase + nt * 16 + mrow) * K + ks * 32 + quad * 8];
#pragma unroll
        for (int mt = 0; mt < 4; ++mt)
#pragma unroll
            for (int nt = 0; nt < 4; ++nt)
                acc[mt][nt] = __builtin_amdgcn_mfma_f32_16x16x32_bf16(
                    af[mt], bfr[nt], acc[mt][nt], 0, 0, 0);
    }
    __syncthreads();   // all waves done reading A before overwrite

#pragma unroll
    for (int nt = 0; nt < 4; ++nt) {
        const int col = colbase + nt * 16 + mrow;
        const float bv = bias[col];
#pragma unroll
        for (int mt = 0; mt < 4; ++mt) {
#pragma unroll
            for (int rI = 0; rI < 4; ++rI) {
                int row = mt * 16 + quad * 4 + rI;
                float v = acc[mt][nt][rI] + bv;
                if (do_selu) v = selu_f(v);
                A[row * LDA + col] = (bf16_t)v;
            }
        }
    }
    __syncthreads();
}

__global__ __launch_bounds__(256) void fmlp_kernel(
    const float* __restrict__ x, const float* __restrict__ statevar,
    const bf16_t* __restrict__ w0b, const bf16_t* __restrict__ w1b,
    const bf16_t* __restrict__ w2b, const bf16_t* __restrict__ w3b,
    const float* __restrict__ fb0, const float* __restrict__ fb1,
    const float* __restrict__ fb2, const float* __restrict__ fb3,
    float* __restrict__ out)
{
    __shared__ bf16_t A[64 * LDA];

    const int tid  = threadIdx.x;
    const int wave = tid >> 6;
    const int lane = tid & 63;
    const int r0   = blockIdx.x * 64;

    // ---- build input tile: [strain(6), strain_dot(6), statevar(20)] ----
    {
        const int r = tid >> 2;       // 0..63
        const int q = tid & 3;        // 8-col group
        const int g = r0 + r;         // global row = b*1000 + s
        const float* xr  = x + g * 13;
        const float* svr = statevar + g * NSV;
#pragma unroll
        for (int i = 0; i < 8; ++i) {
            int c = q * 8 + i;
            float v = (c < 12) ? xr[c + 1] : svr[c - 12];
            A[r * LDA + c] = (bf16_t)v;
        }
    }
    __syncthreads();

    mlp_layer<32>(A, w0b, fb0, wave, lane, true);
    mlp_layer<256>(A, w1b, fb1, wave, lane, true);
    mlp_layer<256>(A, w2b, fb2, wave, lane, true);

    // ---- L3: 256 -> 6 (padded to N=16), waves split rows ----
    {
        const int mrow = lane & 15;
        const int quad = lane >> 4;
        f32x4 acc = (f32x4){0.f, 0.f, 0.f, 0.f};
#pragma unroll
        for (int ks = 0; ks < 8; ++ks) {
            bf16x8 af  = *(const bf16x8*)&A[(wave * 16 + mrow) * LDA + ks * 32 + quad * 8];
            bf16x8 bfr = *(const bf16x8*)&w3b[mrow * 256 + ks * 32 + quad * 8];
            acc = __builtin_amdgcn_mfma_f32_16x16x32_bf16(af, bfr, acc, 0, 0, 0);
        }
        const int col = mrow;
        if (col < 6) {
            const float bv = fb3[col];
#pragma unroll
            for (int rI = 0; rI < 4; ++rI) {
                int row = wave * 16 + quad * 4 + rI;
                int g = r0 + row;
                out[g * 6 + col] = acc[rI] + bv;
            }
        }
    }
}

// ---------------------------------------------------------------------------
extern "C" void kernel_launch(void* const* d_in, const int* in_sizes, int n_in,
                              void* d_out, int out_size, void* d_ws, size_t ws_size,
                              hipStream_t stream)
{
    const float* x   = (const float*)d_in[0];
    const float* gw0 = (const float*)d_in[1];
    const float* gb0 = (const float*)d_in[2];
    const float* gw1 = (const float*)d_in[3];
    const float* gb1 = (const float*)d_in[4];
    const float* gw2 = (const float*)d_in[5];
    const float* gb2 = (const float*)d_in[6];
    const float* gw3 = (const float*)d_in[7];
    const float* gb3 = (const float*)d_in[8];
    const float* fw0 = (const float*)d_in[9];
    const float* fb0 = (const float*)d_in[10];
    const float* fw1 = (const float*)d_in[11];
    const float* fb1 = (const float*)d_in[12];
    const float* fw2 = (const float*)d_in[13];
    const float* fb2 = (const float*)d_in[14];
    const float* fw3 = (const float*)d_in[15];
    const float* fb3 = (const float*)d_in[16];

    // workspace layout
    float* statevar = (float*)d_ws;                              // 256*1000*20 fp32
    bf16_t* w0b = (bf16_t*)((char*)d_ws + 20480000);
    bf16_t* w1b = w0b + 256 * 32;
    bf16_t* w2b = w1b + 256 * 256;
    bf16_t* w3b = w2b + 256 * 256;

    prep_weights<<<64, 256, 0, stream>>>(fw0, fw1, fw2, fw3, w0b, w1b, w2b, w3b);
    rnn_kernel<<<256, 512, 0, stream>>>(x, gw0, gb0, gw1, gb1, gw2, gb2, gw3, gb3, statevar);
    fmlp_kernel<<<4000, 256, 0, stream>>>(x, statevar, w0b, w1b, w2b, w3b,
                                          fb0, fb1, fb2, fb3, (float*)d_out);
}

// Round 3
// 1693.926 us; speedup vs baseline: 1.4295x; 1.4295x over previous
//
#include <hip/hip_runtime.h>

#define NSV 20
#define SS  1000

typedef __bf16 bf16_t;
typedef __bf16 bf16x8 __attribute__((ext_vector_type(8)));
typedef float  f32x4  __attribute__((ext_vector_type(4)));

__device__ __forceinline__ float selu_f(float v) {
    const float scale = 1.0507009873554805f;
    const float alpha = 1.6732632423543772f;
    return v > 0.f ? scale * v : scale * alpha * expm1f(v);
}

// ---------------------------------------------------------------------------
// RNN kernel: one block per batch row, 512 threads (8 waves/CU).
// Threads (4j..4j+3) compute hidden unit j; each holds a 32-wide slice of the
// weight row in registers. Bank-conflict-free via quarter-rotated LDS reads;
// the rotation is baked into the weight LOAD order so every register index in
// the inner loop is a compile-time constant (no scratch demotion).
// ---------------------------------------------------------------------------
__global__ __launch_bounds__(512, 2) void rnn_kernel(
    const float* __restrict__ x,
    const float* __restrict__ gw0, const float* __restrict__ gb0,
    const float* __restrict__ gw1, const float* __restrict__ gb1,
    const float* __restrict__ gw2, const float* __restrict__ gb2,
    const float* __restrict__ gw3, const float* __restrict__ gb3,
    float* __restrict__ statevar)
{
    const int b   = blockIdx.x;
    const int tid = threadIdx.x;
    const int j   = tid >> 2;   // hidden unit 0..127
    const int q   = tid & 3;    // quarter 0..3

    __shared__ __align__(16) float h0buf[28];   // [eps(6), sv(20), pad0(2)]
    __shared__ __align__(16) float hA[128];
    __shared__ __align__(16) float hB[128];
    __shared__ __align__(16) float hC[128];
    __shared__ float sdt[2];

    // ---- weights into registers, rotated column order (static reg indices) --
    float w0[7];
#pragma unroll
    for (int i = 0; i < 7; ++i) {
        int c = q * 7 + i;                      // 0..27
        w0[i] = (c < 26) ? gw0[j * 26 + c] : 0.f;
    }
    float w1[32], w2[32], w3[32];
#pragma unroll
    for (int i = 0; i < 8; ++i) {
        const int cg = ((i + 2 * q) & 7) * 4;   // rotated column group
#pragma unroll
        for (int k = 0; k < 4; ++k)
            w1[i * 4 + k] = gw1[j * 128 + q * 32 + cg + k];
    }
#pragma unroll
    for (int i = 0; i < 8; ++i) {
        const int cg = ((i + 2 * q) & 7) * 4;
#pragma unroll
        for (int k = 0; k < 4; ++k)
            w2[i * 4 + k] = gw2[j * 128 + q * 32 + cg + k];
    }
    if (j < NSV) {
#pragma unroll
        for (int i = 0; i < 8; ++i) {
            const int cg = ((i + 2 * q) & 7) * 4;
#pragma unroll
            for (int k = 0; k < 4; ++k)
                w3[i * 4 + k] = gw3[j * 128 + q * 32 + cg + k];
        }
    }
    const float b0 = gb0[j];
    const float b1 = gb1[j];
    const float b2 = gb2[j];
    const float b3 = (j < NSV) ? gb3[j] : 0.f;

    const float* xb = x + b * (SS * 13);

    // ---- init: h0 = [eps(0), sv0=0, pad=0], dt(0), statevar[:,0,:]=0 ----
    if (tid < 6)                 h0buf[tid] = xb[1 + tid];
    else if (tid < 28)           h0buf[tid] = 0.f;
    if (tid == 28)               sdt[0] = xb[13] - xb[0];
    if (tid < NSV)               statevar[b * (SS * NSV) + tid] = 0.f;
    __syncthreads();

    // 32-wide dot: LDS address rotated per quarter (conflict-free broadcast),
    // register indices all literal.
#define DOT32(W, BASE, OUT) do {                                    \
        const float4* h4_ = (const float4*)(BASE);                  \
        float s0_ = 0.f, s1_ = 0.f, s2_ = 0.f, s3_ = 0.f;           \
        _Pragma("unroll")                                           \
        for (int i_ = 0; i_ < 8; ++i_) {                            \
            float4 hv_ = h4_[(i_ + 2 * q) & 7];                     \
            s0_ = fmaf(W[4*i_+0], hv_.x, s0_);                      \
            s1_ = fmaf(W[4*i_+1], hv_.y, s1_);                      \
            s2_ = fmaf(W[4*i_+2], hv_.z, s2_);                      \
            s3_ = fmaf(W[4*i_+3], hv_.w, s3_);                      \
        }                                                           \
        OUT = (s0_ + s1_) + (s2_ + s3_);                            \
    } while (0)

    for (int t = 0; t < SS - 1; ++t) {
        // L0: 28 -> 128 (h0buf[26..27] are permanent zeros)
        {
            float s0 = 0.f, s1 = 0.f;
            const float* hh = &h0buf[q * 7];
#pragma unroll
            for (int i = 0; i < 6; i += 2) {
                s0 = fmaf(w0[i + 0], hh[i + 0], s0);
                s1 = fmaf(w0[i + 1], hh[i + 1], s1);
            }
            s0 = fmaf(w0[6], hh[6], s0);
            float s = s0 + s1;
            s += __shfl_xor(s, 1, 64);
            s += __shfl_xor(s, 2, 64);
            if (q == 0) hA[j] = selu_f(s + b0);
        }
        __syncthreads();

        // L1: 128 -> 128  (hA -> hB)
        {
            float s;
            DOT32(w1, &hA[q * 32], s);
            s += __shfl_xor(s, 1, 64);
            s += __shfl_xor(s, 2, 64);
            if (q == 0) hB[j] = selu_f(s + b1);
        }
        __syncthreads();

        // L2: 128 -> 128  (hB -> hC)
        {
            float s;
            DOT32(w2, &hB[q * 32], s);
            s += __shfl_xor(s, 1, 64);
            s += __shfl_xor(s, 2, 64);
            if (q == 0) hC[j] = selu_f(s + b2);
        }
        __syncthreads();

        // L3: 128 -> 20, integrate sv into h0buf; prefetch eps/dt for t+1
        if (j < NSV) {
            float s;
            DOT32(w3, &hC[q * 32], s);
            s += __shfl_xor(s, 1, 64);
            s += __shfl_xor(s, 2, 64);
            if (q == 0) {
                float svd = s + b3;
                float ns  = h0buf[6 + j] + sdt[t & 1] * svd;
                h0buf[6 + j] = ns;
                statevar[b * (SS * NSV) + (t + 1) * NSV + j] = ns;
            }
        }
        if (tid >= 128 && tid < 134)
            h0buf[tid - 128] = xb[(t + 1) * 13 + 1 + (tid - 128)];
        if (tid == 140 && t + 2 < SS)
            sdt[(t + 1) & 1] = xb[(t + 2) * 13] - xb[(t + 1) * 13];
        __syncthreads();
    }
#undef DOT32
}

// ---------------------------------------------------------------------------
// Weight prep: fp32 -> bf16, pad fw3 from [6][256] to [16][256] with zeros.
// ---------------------------------------------------------------------------
__global__ void prep_weights(
    const float* __restrict__ fw0, const float* __restrict__ fw1,
    const float* __restrict__ fw2, const float* __restrict__ fw3,
    bf16_t* __restrict__ w0b, bf16_t* __restrict__ w1b,
    bf16_t* __restrict__ w2b, bf16_t* __restrict__ w3b)
{
    const int i      = blockIdx.x * blockDim.x + threadIdx.x;
    const int stride = gridDim.x * blockDim.x;
    for (int k = i; k < 256 * 32;  k += stride) w0b[k] = (bf16_t)fw0[k];
    for (int k = i; k < 256 * 256; k += stride) w1b[k] = (bf16_t)fw1[k];
    for (int k = i; k < 256 * 256; k += stride) w2b[k] = (bf16_t)fw2[k];
    for (int k = i; k < 16 * 256;  k += stride) {
        int row = k >> 8, col = k & 255;
        w3b[k] = (row < 6) ? (bf16_t)fw3[row * 256 + col] : (bf16_t)0.f;
    }
}

// ---------------------------------------------------------------------------
// Fused F-MLP: 64-row tiles, bf16 MFMA 16x16x32, fp32 accumulate.
// ---------------------------------------------------------------------------
#define LDA 264   // 256 + 8 pad

template <int K>
__device__ __forceinline__ void mlp_layer(
    bf16_t* __restrict__ A, const bf16_t* __restrict__ Wb,
    const float* __restrict__ bias, int wave, int lane, bool do_selu)
{
    f32x4 acc[4][4];
#pragma unroll
    for (int mt = 0; mt < 4; ++mt)
#pragma unroll
        for (int nt = 0; nt < 4; ++nt) acc[mt][nt] = (f32x4){0.f, 0.f, 0.f, 0.f};

    const int colbase = wave * 64;
    const int mrow = lane & 15;
    const int quad = lane >> 4;

#pragma unroll
    for (int ks = 0; ks < K / 32; ++ks) {
        bf16x8 af[4], bfr[4];
#pragma unroll
        for (int mt = 0; mt < 4; ++mt)
            af[mt] = *(const bf16x8*)&A[(mt * 16 + mrow) * LDA + ks * 32 + quad * 8];
#pragma unroll
        for (int nt = 0; nt < 4; ++nt)
            bfr[nt] = *(const bf16x8*)&Wb[(colbase + nt * 16 + mrow) * K + ks * 32 + quad * 8];
#pragma unroll
        for (int mt = 0; mt < 4; ++mt)
#pragma unroll
            for (int nt = 0; nt < 4; ++nt)
                acc[mt][nt] = __builtin_amdgcn_mfma_f32_16x16x32_bf16(
                    af[mt], bfr[nt], acc[mt][nt], 0, 0, 0);
    }
    __syncthreads();   // all waves done reading A before overwrite

#pragma unroll
    for (int nt = 0; nt < 4; ++nt) {
        const int col = colbase + nt * 16 + mrow;
        const float bv = bias[col];
#pragma unroll
        for (int mt = 0; mt < 4; ++mt) {
#pragma unroll
            for (int rI = 0; rI < 4; ++rI) {
                int row = mt * 16 + quad * 4 + rI;
                float v = acc[mt][nt][rI] + bv;
                if (do_selu) v = selu_f(v);
                A[row * LDA + col] = (bf16_t)v;
            }
        }
    }
    __syncthreads();
}

__global__ __launch_bounds__(256) void fmlp_kernel(
    const float* __restrict__ x, const float* __restrict__ statevar,
    const bf16_t* __restrict__ w0b, const bf16_t* __restrict__ w1b,
    const bf16_t* __restrict__ w2b, const bf16_t* __restrict__ w3b,
    const float* __restrict__ fb0, const float* __restrict__ fb1,
    const float* __restrict__ fb2, const float* __restrict__ fb3,
    float* __restrict__ out)
{
    __shared__ bf16_t A[64 * LDA];

    const int tid  = threadIdx.x;
    const int wave = tid >> 6;
    const int lane = tid & 63;
    const int r0   = blockIdx.x * 64;

    // ---- build input tile: [strain(6), strain_dot(6), statevar(20)] ----
    {
        const int r = tid >> 2;       // 0..63
        const int q = tid & 3;        // 8-col group
        const int g = r0 + r;         // global row = b*1000 + s
        const float* xr  = x + g * 13;
        const float* svr = statevar + g * NSV;
#pragma unroll
        for (int i = 0; i < 8; ++i) {
            int c = q * 8 + i;
            float v = (c < 12) ? xr[c + 1] : svr[c - 12];
            A[r * LDA + c] = (bf16_t)v;
        }
    }
    __syncthreads();

    mlp_layer<32>(A, w0b, fb0, wave, lane, true);
    mlp_layer<256>(A, w1b, fb1, wave, lane, true);
    mlp_layer<256>(A, w2b, fb2, wave, lane, true);

    // ---- L3: 256 -> 6 (padded to N=16), waves split rows ----
    {
        const int mrow = lane & 15;
        const int quad = lane >> 4;
        f32x4 acc = (f32x4){0.f, 0.f, 0.f, 0.f};
#pragma unroll
        for (int ks = 0; ks < 8; ++ks) {
            bf16x8 af  = *(const bf16x8*)&A[(wave * 16 + mrow) * LDA + ks * 32 + quad * 8];
            bf16x8 bfr = *(const bf16x8*)&w3b[mrow * 256 + ks * 32 + quad * 8];
            acc = __builtin_amdgcn_mfma_f32_16x16x32_bf16(af, bfr, acc, 0, 0, 0);
        }
        const int col = mrow;
        if (col < 6) {
            const float bv = fb3[col];
#pragma unroll
            for (int rI = 0; rI < 4; ++rI) {
                int row = wave * 16 + quad * 4 + rI;
                int g = r0 + row;
                out[g * 6 + col] = acc[rI] + bv;
            }
        }
    }
}

// ---------------------------------------------------------------------------
extern "C" void kernel_launch(void* const* d_in, const int* in_sizes, int n_in,
                              void* d_out, int out_size, void* d_ws, size_t ws_size,
                              hipStream_t stream)
{
    const float* x   = (const float*)d_in[0];
    const float* gw0 = (const float*)d_in[1];
    const float* gb0 = (const float*)d_in[2];
    const float* gw1 = (const float*)d_in[3];
    const float* gb1 = (const float*)d_in[4];
    const float* gw2 = (const float*)d_in[5];
    const float* gb2 = (const float*)d_in[6];
    const float* gw3 = (const float*)d_in[7];
    const float* gb3 = (const float*)d_in[8];
    const float* fw0 = (const float*)d_in[9];
    const float* fb0 = (const float*)d_in[10];
    const float* fw1 = (const float*)d_in[11];
    const float* fb1 = (const float*)d_in[12];
    const float* fw2 = (const float*)d_in[13];
    const float* fb2 = (const float*)d_in[14];
    const float* fw3 = (const float*)d_in[15];
    const float* fb3 = (const float*)d_in[16];

    // workspace layout
    float* statevar = (float*)d_ws;                              // 256*1000*20 fp32
    bf16_t* w0b = (bf16_t*)((char*)d_ws + 20480000);
    bf16_t* w1b = w0b + 256 * 32;
    bf16_t* w2b = w1b + 256 * 256;
    bf16_t* w3b = w2b + 256 * 256;

    prep_weights<<<64, 256, 0, stream>>>(fw0, fw1, fw2, fw3, w0b, w1b, w2b, w3b);
    rnn_kernel<<<256, 512, 0, stream>>>(x, gw0, gb0, gw1, gb1, gw2, gb2, gw3, gb3, statevar);
    fmlp_kernel<<<4000, 256, 0, stream>>>(x, statevar, w0b, w1b, w2b, w3b,
                                          fb0, fb1, fb2, fb3, (float*)d_out);
}